// Round 7
// baseline (544.069 us; speedup 1.0000x reference)
//
#include <hip/hip_runtime.h>

#define M_DIM 4096
#define K_DIM 4096
#define N_DIM 11008
#define BM 128
#define BN 128
#define BK 64    // bytes of K per tile iteration (int8)
#define NTILES (K_DIM / BK)   // 64

typedef int v4i  __attribute__((ext_vector_type(4)));

// s_waitcnt immediates (gfx90a+ encoding: vmcnt[3:0]+[15:14], exp[6:4], lgkm[13:8])
#define WAIT_VM4 0x3F74   // vmcnt<=4  (one stage() = 4 loads still in flight)
#define WAIT_VM0 0x3F70   // vmcnt<=0

__device__ __forceinline__ void load_lds16(const void* g, void* l) {
    __builtin_amdgcn_global_load_lds(
        (const __attribute__((address_space(1))) void*)g,
        (__attribute__((address_space(3))) void*)l,
        16, 0, 0);
}

__device__ __forceinline__ unsigned int pack4(int4 v, int zp) {
    return ((unsigned int)(v.x - zp) & 0xFF)
         | (((unsigned int)(v.y - zp) & 0xFF) << 8)
         | (((unsigned int)(v.z - zp) & 0xFF) << 16)
         | (((unsigned int)(v.w - zp) & 0xFF) << 24);
}

// Fused pack: one launch covers x (with zero-point) then w (zp=0).
__global__ void pack_both_kernel(const int* __restrict__ x, const int* __restrict__ w,
                                 unsigned int* __restrict__ x8, unsigned int* __restrict__ w8,
                                 const int* __restrict__ zp_p, int nx16, int nw16) {
    int i = blockIdx.x * blockDim.x + threadIdx.x;
    if (i < nx16) {
        const int zp = zp_p[0];
        const int4* p = (const int4*)x + i * 4;
        uint4 o;
        o.x = pack4(p[0], zp);
        o.y = pack4(p[1], zp);
        o.z = pack4(p[2], zp);
        o.w = pack4(p[3], zp);
        ((uint4*)x8)[i] = o;
    } else {
        int j = i - nx16;
        if (j >= nw16) return;
        const int4* p = (const int4*)w + j * 4;
        uint4 o;
        o.x = pack4(p[0], 0);
        o.y = pack4(p[1], 0);
        o.z = pack4(p[2], 0);
        o.w = pack4(p[3], 0);
        ((uint4*)w8)[j] = o;
    }
}

// R6 post-mortem conclusion: all 32x32-based configs are TLP-starved at
// 2 waves/SIMD (neither LDS 51-73% nor MFMA 39-44% saturated; barriers,
// buffering, prefetch depth, L2 traffic individually falsified). The
// register wall (acc[4][2]=128 AGPR) caps waves/SIMD at 2.
//
// Fix: mfma_i32_16x16x64_i8. Same 32768 MACs/instr, but a 64x64 wave
// tile = 4x4 fragments -> each fragment feeds 4 MFMAs -> 0.5 ds_reads
// per MFMA (vs 0.75) AND acc = 64 AGPR -> ~150 regs -> 3 waves/SIMD,
// 3 blocks/CU (dbuf 32 KB x 3 = 96 <= 160 KB LDS). Balanced pipes:
// per-CU MFMA ~225k cyc (16x16 rate 3944 TOPS), LDS ~218k cyc.
//
// Operand layout (family pattern, 32x32x32 harness-verified; m89-verified
// C/D): A/B fragment: m(or n) = lane&15, k bytes [(lane>>4)*16, +16).
// C/D 16x16: col = lane&15, row = (lane>>4)*4 + reg.
//
// LDS swizzle (R4-fixed, kept): granule g of row r stored at position
// g ^ ((r>>1)&3) in the 4-granule 64B row (slot = r*4 + pos); the same
// involution is pre-applied to the GLOBAL source granule so
// global_load_lds's linear dest receives swizzled data.
__global__ __launch_bounds__(256, 3) void gemm_i8_kernel(
    const signed char* __restrict__ A8,   // [M][K] int8 (x - zp)
    const signed char* __restrict__ B8,   // [N][K] int8 (w)
    const float* __restrict__ bias,
    const float* __restrict__ xs_p, const float* __restrict__ ws_p,
    const float* __restrict__ os_p, const int* __restrict__ ozp_p,
    int* __restrict__ out) {
    __shared__ v4i As0[BM * BK / 16];   // 8 KB each
    __shared__ v4i Bs0[BN * BK / 16];
    __shared__ v4i As1[BM * BK / 16];
    __shared__ v4i Bs1[BN * BK / 16];   // 32 KB total -> 3 blocks/CU (96 of 160 KB)

    const int tid  = threadIdx.x;
    const int lane = tid & 63;
    const int wave = tid >> 6;

    // ---- 2D XCD-aware swizzle: 2752 blocks = 8 XCD x 344 local.
    // Per XCD: 4 consecutive m-tiles share each B panel (co-resident ->
    // L2 reuse); the XCD's A panel (512 rows x 4K = 2 MB) stays L2-resident
    // across the n sweep.
    const int bid   = blockIdx.x;
    const int xcd   = bid & 7;
    const int local = bid >> 3;                    // [0, 344)
    const int m_blk = xcd * 4 + (local & 3);       // [0, 32)
    const int n_blk = local >> 2;                  // [0, 86)
    const int m0 = m_blk * BM;
    const int n0 = n_blk * BN;

    // ---- staging addresses: per thread 2 A granules + 2 B granules per tile ----
    long offA[2], offB[2];
    int  ldsA[2], ldsB[2];
#pragma unroll
    for (int j = 0; j < 2; ++j) {
        const int s   = tid + 256 * j;             // slot [0,512)
        const int row = s >> 2;
        const int gg  = (s & 3) ^ ((row >> 1) & 3); // pre-swizzled source granule
        offA[j] = (long)(m0 + row) * K_DIM + gg * 16;
        offB[j] = (long)(n0 + row) * K_DIM + gg * 16;
        ldsA[j] = s;
        ldsB[j] = s;
    }

    // ---- fragment slots for mfma_i32_16x16x64_i8 ----
    // A/B operand: m(or n) = lane&15, k bytes [(lane>>4)*16, +16)
    const int waveM = wave >> 1, waveN = wave & 1;
    const int l15 = lane & 15, kg = lane >> 4;     // k-granule 0..3
    int aSlot[4], bSlot[4];
#pragma unroll
    for (int t = 0; t < 4; ++t) {
        const int rA = waveM * 64 + t * 16 + l15;
        const int rB = waveN * 64 + t * 16 + l15;
        aSlot[t] = rA * 4 + (kg ^ ((rA >> 1) & 3));
        bSlot[t] = rB * 4 + (kg ^ ((rB >> 1) & 3));
    }

    v4i acc[4][4];
#pragma unroll
    for (int mi = 0; mi < 4; ++mi)
#pragma unroll
        for (int ni = 0; ni < 4; ++ni)
#pragma unroll
            for (int r = 0; r < 4; ++r) acc[mi][ni][r] = 0;

    // ---- helpers ----
    auto stage = [&](int tile, v4i* Asb, v4i* Bsb) {
        const long koff = (long)tile * BK;
#pragma unroll
        for (int j = 0; j < 2; ++j) load_lds16(A8 + offA[j] + koff, (char*)(Asb + ldsA[j]));
#pragma unroll
        for (int j = 0; j < 2; ++j) load_lds16(B8 + offB[j] + koff, (char*)(Bsb + ldsB[j]));
    };
    // 8 ds_reads feed 16 MFMAs (0.5 reads/MFMA); 16 independent acc chains.
    auto compute = [&](const v4i* Asb, const v4i* Bsb) {
        v4i a[4], b[4];
#pragma unroll
        for (int t = 0; t < 4; ++t) a[t] = Asb[aSlot[t]];
#pragma unroll
        for (int t = 0; t < 4; ++t) b[t] = Bsb[bSlot[t]];
#pragma unroll
        for (int mi = 0; mi < 4; ++mi)
#pragma unroll
            for (int ni = 0; ni < 4; ++ni)
                acc[mi][ni] = __builtin_amdgcn_mfma_i32_16x16x64_i8(
                    a[mi], b[ni], acc[mi][ni], 0, 0, 0);
    };

    // ---- async double-buffered pipeline, counted vmcnt (never drains to 0
    // in the main loop: next tile's 4 loads stay in flight across barriers) ----
    stage(0, As0, Bs0);          // 4 vm-ops in flight
    stage(1, As1, Bs1);          // 8 in flight

#pragma unroll 1
    for (int kk = 0; kk < 31; ++kk) {
        const int k = 2 * kk;
        // even: consume buf0
        __builtin_amdgcn_s_waitcnt(WAIT_VM4);   // tile k landed; tile k+1 still flying
        __builtin_amdgcn_s_barrier();
        compute(As0, Bs0);
        __builtin_amdgcn_s_barrier();           // everyone done reading buf0
        stage(k + 2, As0, Bs0);
        // odd: consume buf1
        __builtin_amdgcn_s_waitcnt(WAIT_VM4);   // tile k+1 landed; tile k+2 flying
        __builtin_amdgcn_s_barrier();
        compute(As1, Bs1);
        __builtin_amdgcn_s_barrier();           // everyone done reading buf1
        stage(k + 3, As1, Bs1);
    }
    // peeled tail: tiles 62, 63
    __builtin_amdgcn_s_waitcnt(WAIT_VM4);
    __builtin_amdgcn_s_barrier();
    compute(As0, Bs0);
    __builtin_amdgcn_s_waitcnt(WAIT_VM0);
    __builtin_amdgcn_s_barrier();
    compute(As1, Bs1);

    // ---- epilogue: dequant + bias, requant to [0,255] ----
    // C/D 16x16: col = lane&15, row = (lane>>4)*4 + reg   (m89-verified)
    const float scale  = xs_p[0] * ws_p[0];
    const float inv_os = 1.0f / os_p[0];
    const int   ozp    = ozp_p[0];
#pragma unroll
    for (int mi = 0; mi < 4; ++mi) {
        const int rbase = m0 + waveM * 64 + mi * 16 + 4 * kg;
#pragma unroll
        for (int ni = 0; ni < 4; ++ni) {
            const int col = n0 + waveN * 64 + ni * 16 + l15;
            const float bv = bias[col];
#pragma unroll
            for (int r = 0; r < 4; ++r) {
                const int row = rbase + r;
                float y = (float)acc[mi][ni][r] * scale + bv;
                int q = (int)rintf(y * inv_os) + ozp;
                q = q < 0 ? 0 : (q > 255 ? 255 : q);
                out[(long)row * N_DIM + col] = q;
            }
        }
    }
}

extern "C" void kernel_launch(void* const* d_in, const int* in_sizes, int n_in,
                              void* d_out, int out_size, void* d_ws, size_t ws_size,
                              hipStream_t stream) {
    const int*   x_q  = (const int*)d_in[0];
    const int*   w_q  = (const int*)d_in[1];
    const float* bias = (const float*)d_in[2];
    const float* xs   = (const float*)d_in[3];
    const float* wsc  = (const float*)d_in[4];
    const float* os   = (const float*)d_in[5];
    const int*   xzp  = (const int*)d_in[6];
    const int*   ozp  = (const int*)d_in[7];

    signed char* x8 = (signed char*)d_ws;                               // 16 MB
    signed char* w8 = (signed char*)d_ws + (size_t)M_DIM * K_DIM;       // 45 MB

    const int nx16 = M_DIM * K_DIM / 16;
    const int nw16 = N_DIM * K_DIM / 16;
    const int npack = nx16 + nw16;
    pack_both_kernel<<<(npack + 255) / 256, 256, 0, stream>>>(
        x_q, w_q, (unsigned int*)x8, (unsigned int*)w8, xzp, nx16, nw16);

    const int nblocks = (M_DIM / BM) * (N_DIM / BN);   // 32 * 86 = 2752
    gemm_i8_kernel<<<nblocks, 256, 0, stream>>>(x8, w8, bias, xs, wsc, os, ozp, (int*)d_out);
}